// Round 9
// baseline (528.750 us; speedup 1.0000x reference)
//
#include <hip/hip_runtime.h>
#include <hip/hip_bf16.h>
#include <cstddef>

#define T_TOK 2048
#define H_DIM 768
#define NEXP 16
#define KSEL 4
#define I_DIM 768
#define TWO_I 1536
#define NSLOT (T_TOK*KSEL)
#define ALPHA 1.702f
#define LIMIT 7.0f
#define EPS_RMS 1e-5f
#define BM 128

typedef _Float16 f16;
typedef _Float16 half8 __attribute__((ext_vector_type(8)));
typedef float f32x4 __attribute__((ext_vector_type(4)));

// ---------------- Kernel 1: RMSNorm + router (fp32) + residual init ----------------
__global__ __launch_bounds__(256) void k_rms_router(
    const float* __restrict__ x, const float* __restrict__ scale,
    const float* __restrict__ gw, const float* __restrict__ gb,
    f16* __restrict__ th, float* __restrict__ out,
    int* __restrict__ topk_idx, float* __restrict__ topk_w)
{
    int t = blockIdx.x;
    int tid = threadIdx.x;
    int lane = tid & 63, wid = tid >> 6;
    __shared__ float ts[H_DIM];
    __shared__ float red[8];
    __shared__ float logits[NEXP];

    const float* xr = x + (size_t)t * H_DIM;
    float v0 = xr[tid], v1 = xr[tid + 256], v2 = xr[tid + 512];
    float ss = v0*v0 + v1*v1 + v2*v2;
    #pragma unroll
    for (int m = 32; m >= 1; m >>= 1) ss += __shfl_xor(ss, m, 64);
    if (lane == 0) red[wid] = ss;
    __syncthreads();
    if (tid == 0) {
        float tot = red[0] + red[1] + red[2] + red[3];
        red[4] = rsqrtf(tot / (float)H_DIM + EPS_RMS);
    }
    __syncthreads();
    float rinv = red[4];
    float t0 = v0 * rinv * scale[tid];
    float t1 = v1 * rinv * scale[tid + 256];
    float t2 = v2 * rinv * scale[tid + 512];
    ts[tid] = t0; ts[tid + 256] = t1; ts[tid + 512] = t2;
    size_t base = (size_t)t * H_DIM;
    th[base + tid] = (f16)t0;
    th[base + tid + 256] = (f16)t1;
    th[base + tid + 512] = (f16)t2;
    float* op = out + base;
    op[tid] = v0; op[tid + 256] = v1; op[tid + 512] = v2;
    __syncthreads();

    #pragma unroll
    for (int ee = 0; ee < 4; ++ee) {
        int e = wid * 4 + ee;
        const float* g = gw + (size_t)e * H_DIM;
        float p = 0.f;
        for (int i = lane; i < H_DIM; i += 64) p += ts[i] * g[i];
        #pragma unroll
        for (int m = 32; m >= 1; m >>= 1) p += __shfl_xor(p, m, 64);
        if (lane == 0) logits[e] = p + gb[e];
    }
    __syncthreads();

    if (tid == 0) {
        float lg[NEXP];
        #pragma unroll
        for (int e = 0; e < NEXP; ++e) lg[e] = logits[e];
        float vals[KSEL]; int idx[KSEL];
        #pragma unroll
        for (int k = 0; k < KSEL; ++k) {
            float best = -1e30f; int bi = 0;
            for (int e = 0; e < NEXP; ++e)
                if (lg[e] > best) { best = lg[e]; bi = e; }   // strict > => lowest index on ties
            vals[k] = best; idx[k] = bi; lg[bi] = -1e30f;
        }
        float mx = vals[0], sum = 0.f, ex[KSEL];
        #pragma unroll
        for (int k = 0; k < KSEL; ++k) { ex[k] = expf(vals[k] - mx); sum += ex[k]; }
        float inv = 1.f / sum;
        #pragma unroll
        for (int k = 0; k < KSEL; ++k) {
            topk_idx[t * KSEL + k] = idx[k];
            topk_w[t * KSEL + k] = ex[k] * inv;   // softmax/K * K cancels
        }
    }
}

// ---------------- Kernel 2: fused count + scan + scatter (1 block) ----------------
__global__ __launch_bounds__(256) void k_route(
    const int* __restrict__ topk_idx, const float* __restrict__ topk_w,
    int* __restrict__ offsets,
    int* __restrict__ expert_tokens, float* __restrict__ expert_wts)
{
    __shared__ int cnt[NEXP];
    __shared__ int cur[NEXP];
    int tid = threadIdx.x;
    if (tid < NEXP) cnt[tid] = 0;
    __syncthreads();
    int base = tid * 32;                       // NSLOT = 256*32
    for (int j = 0; j < 32; ++j) atomicAdd(&cnt[topk_idx[base + j]], 1);
    __syncthreads();
    if (tid == 0) {
        int acc = 0;
        for (int e = 0; e < NEXP; ++e) {
            offsets[e] = acc; cur[e] = acc; acc += cnt[e];
        }
        offsets[NEXP] = acc;
    }
    __syncthreads();
    for (int j = 0; j < 32; ++j) {
        int i = base + j;
        int e = topk_idx[i];
        int slot = atomicAdd(&cur[e], 1);
        expert_tokens[slot] = i >> 2;          // i = t*KSEL + k
        expert_wts[slot] = topk_w[i];
    }
}

// ---------------- Kernel 3: GEMM1 (H->2I) fp16 MFMA, depth-2 prefetch, XCD swizzle ----------------
__global__ __launch_bounds__(256, 4) void k_gemm1(
    const f16* __restrict__ th, const float* __restrict__ w1,
    const float* __restrict__ b1,
    const int* __restrict__ expert_tokens, const int* __restrict__ offsets,
    f16* __restrict__ h_buf)
{
    // bijective XCD-chunked swizzle: 3072 blocks = 8 XCDs x 384; m-tile (y) fastest
    int lid = blockIdx.x + 12 * (blockIdx.y + 16 * blockIdx.z);
    int tl = (lid & 7) * 384 + (lid >> 3);
    int by = tl & 15;
    int bx = (tl >> 4) % 12;
    int e  = tl / 192;

    int beg = offsets[e];
    int cnt = offsets[e + 1] - beg;
    int m0 = by * BM;
    if (m0 >= cnt) return;
    int n0 = bx * 64;
    int rows = min(BM, cnt - m0);

    __shared__ f16 A_h[BM][40];
    __shared__ f16 Bg_h[64][40];
    __shared__ f16 Bn_h[64][40];
    __shared__ int toks[BM];

    int tid = threadIdx.x;
    int w = tid >> 6, lane = tid & 63;
    if (tid < BM) toks[tid] = (tid < rows) ? expert_tokens[beg + m0 + tid] : -1;
    __syncthreads();

    int arow = tid >> 2, ach = tid & 3;
    int tokA0 = toks[arow], tokA1 = toks[arow + 64];
    int fr = lane & 15, fg = lane >> 4;
    int wr = w >> 1, wc = w & 1;

    const float* bgp = w1 + ((size_t)e * H_DIM + w * 8) * TWO_I + n0 + lane;

    half8 z8;
    #pragma unroll
    for (int j = 0; j < 8; ++j) z8[j] = (f16)0.f;

    f32x4 zero4 = {0.f, 0.f, 0.f, 0.f};
    f32x4 accg[4][2], accn[4][2];
    #pragma unroll
    for (int mi = 0; mi < 4; ++mi)
        #pragma unroll
        for (int s = 0; s < 2; ++s) { accg[mi][s] = zero4; accn[mi][s] = zero4; }

    half8 pah0A, pah1A, pah0B, pah1B;
    float pbgA[8], pbnA[8], pbgB[8], pbnB[8];

#define G1_PRELOAD(S, KK)                                                       \
    {                                                                           \
        pah0##S = (tokA0 >= 0) ? *(const half8*)(th + (size_t)tokA0 * H_DIM + (KK) + ach * 8) : z8; \
        pah1##S = (tokA1 >= 0) ? *(const half8*)(th + (size_t)tokA1 * H_DIM + (KK) + ach * 8) : z8; \
        _Pragma("unroll")                                                       \
        for (int j = 0; j < 8; ++j) {                                           \
            pbg##S[j] = bgp[(size_t)((KK) + j) * TWO_I];                        \
            pbn##S[j] = bgp[(size_t)((KK) + j) * TWO_I + I_DIM];                \
        }                                                                       \
    }

#define G1_STAGE(S)                                                             \
    {                                                                           \
        *(half8*)&A_h[arow][ach * 8] = pah0##S;                                 \
        *(half8*)&A_h[arow + 64][ach * 8] = pah1##S;                            \
        half8 vg, vn;                                                           \
        _Pragma("unroll")                                                       \
        for (int j = 0; j < 8; ++j) { vg[j] = (f16)pbg##S[j]; vn[j] = (f16)pbn##S[j]; } \
        *(half8*)&Bg_h[lane][w * 8] = vg;                                       \
        *(half8*)&Bn_h[lane][w * 8] = vn;                                       \
    }

#define G1_COMPUTE()                                                            \
    {                                                                           \
        half8 ah[4];                                                            \
        _Pragma("unroll")                                                       \
        for (int mi = 0; mi < 4; ++mi)                                          \
            ah[mi] = *(const half8*)&A_h[wr * 64 + mi * 16 + fr][fg * 8];       \
        _Pragma("unroll")                                                       \
        for (int s = 0; s < 2; ++s) {                                           \
            int nb = wc * 32 + s * 16 + fr;                                     \
            half8 bgh = *(const half8*)&Bg_h[nb][fg * 8];                       \
            half8 bnh = *(const half8*)&Bn_h[nb][fg * 8];                       \
            _Pragma("unroll")                                                   \
            for (int mi = 0; mi < 4; ++mi) {                                    \
                accg[mi][s] = __builtin_amdgcn_mfma_f32_16x16x32_f16(ah[mi], bgh, accg[mi][s], 0, 0, 0); \
                accn[mi][s] = __builtin_amdgcn_mfma_f32_16x16x32_f16(ah[mi], bnh, accn[mi][s], 0, 0, 0); \
            }                                                                   \
        }                                                                       \
    }

    G1_PRELOAD(A, 0);
    G1_STAGE(A);
    __syncthreads();
    G1_PRELOAD(B, 32);

    for (int kk = 0; kk < H_DIM; kk += 64) {
        if (kk + 64 < H_DIM) G1_PRELOAD(A, kk + 64);   // 2 compute-phases of flight
        G1_COMPUTE();                                   // LDS = tile kk
        __syncthreads();
        G1_STAGE(B);                                    // tile kk+32
        __syncthreads();
        if (kk + 96 < H_DIM) G1_PRELOAD(B, kk + 96);
        G1_COMPUTE();                                   // LDS = tile kk+32
        __syncthreads();
        if (kk + 64 < H_DIM) { G1_STAGE(A); __syncthreads(); }
    }
#undef G1_PRELOAD
#undef G1_STAGE
#undef G1_COMPUTE

    // epilogue: bias + SwiGLU (C/D map m89: col=lane&15, row=(lane>>4)*4+reg)
    const float* b1p = b1 + (size_t)e * TWO_I + n0;
    #pragma unroll
    for (int mi = 0; mi < 4; ++mi) {
        #pragma unroll
        for (int s = 0; s < 2; ++s) {
            #pragma unroll
            for (int r4 = 0; r4 < 4; ++r4) {
                int rt = wr * 64 + mi * 16 + fg * 4 + r4;
                if (rt >= rows) continue;
                int slot = beg + m0 + rt;
                int c = wc * 32 + s * 16 + fr;
                float hg = accg[mi][s][r4] + b1p[c];
                float hl2 = accn[mi][s][r4] + b1p[I_DIM + c];
                hg = fminf(hg, LIMIT);
                hl2 = fminf(fmaxf(hl2, -LIMIT), LIMIT);
                float sg = 1.f / (1.f + expf(-ALPHA * hg));
                h_buf[(size_t)slot * I_DIM + n0 + c] = (f16)(hg * sg * (hl2 + 1.f));
            }
        }
    }
}

// ---------------- Kernel 4: GEMM2 (I->H) fp16 MFMA, depth-2 prefetch, XCD swizzle ----------------
__global__ __launch_bounds__(256, 4) void k_gemm2(
    const f16* __restrict__ h_buf, const float* __restrict__ w2,
    const float* __restrict__ b2,
    const int* __restrict__ expert_tokens, const float* __restrict__ expert_wts,
    const int* __restrict__ offsets, float* __restrict__ out)
{
    int lid = blockIdx.x + 12 * (blockIdx.y + 16 * blockIdx.z);
    int tl = (lid & 7) * 384 + (lid >> 3);
    int by = tl & 15;
    int bx = (tl >> 4) % 12;
    int e  = tl / 192;

    int beg = offsets[e];
    int cnt = offsets[e + 1] - beg;
    int m0 = by * BM;
    if (m0 >= cnt) return;
    int n0 = bx * 64;
    int rows = min(BM, cnt - m0);

    __shared__ f16 A_h[BM][40];
    __shared__ f16 B_h[64][40];
    __shared__ int   toks[BM];
    __shared__ float wts[BM];

    int tid = threadIdx.x;
    int w = tid >> 6, lane = tid & 63;
    if (tid < BM) {
        bool ok = tid < rows;
        toks[tid] = ok ? expert_tokens[beg + m0 + tid] : -1;
        wts[tid]  = ok ? expert_wts[beg + m0 + tid] : 0.f;
    }
    __syncthreads();

    int arow = tid >> 2, ach = tid & 3;
    bool aok0 = arow < rows, aok1 = (arow + 64) < rows;
    int fr = lane & 15, fg = lane >> 4;
    int r0 = w * 32;

    const float* bp = w2 + ((size_t)e * I_DIM + w * 8) * H_DIM + n0 + lane;

    half8 z8;
    #pragma unroll
    for (int j = 0; j < 8; ++j) z8[j] = (f16)0.f;

    f32x4 zero4 = {0.f, 0.f, 0.f, 0.f};
    f32x4 acc[2][4];
    #pragma unroll
    for (int mi = 0; mi < 2; ++mi)
        #pragma unroll
        for (int s = 0; s < 4; ++s) acc[mi][s] = zero4;

    half8 pah0A, pah1A, pah0B, pah1B;
    float pbA[8], pbB[8];

#define G2_PRELOAD(S, KK)                                                       \
    {                                                                           \
        pah0##S = aok0 ? *(const half8*)(h_buf + (size_t)(beg + m0 + arow) * I_DIM + (KK) + ach * 8) : z8; \
        pah1##S = aok1 ? *(const half8*)(h_buf + (size_t)(beg + m0 + arow + 64) * I_DIM + (KK) + ach * 8) : z8; \
        _Pragma("unroll")                                                       \
        for (int j = 0; j < 8; ++j) pb##S[j] = bp[(size_t)((KK) + j) * H_DIM];  \
    }

#define G2_STAGE(S)                                                             \
    {                                                                           \
        *(half8*)&A_h[arow][ach * 8] = pah0##S;                                 \
        *(half8*)&A_h[arow + 64][ach * 8] = pah1##S;                            \
        half8 vb;                                                               \
        _Pragma("unroll")                                                       \
        for (int j = 0; j < 8; ++j) vb[j] = (f16)pb##S[j];                      \
        *(half8*)&B_h[lane][w * 8] = vb;                                        \
    }

#define G2_COMPUTE()                                                            \
    {                                                                           \
        half8 ah[2];                                                            \
        _Pragma("unroll")                                                       \
        for (int mi = 0; mi < 2; ++mi)                                          \
            ah[mi] = *(const half8*)&A_h[r0 + mi * 16 + fr][fg * 8];            \
        _Pragma("unroll")                                                       \
        for (int s = 0; s < 4; ++s) {                                           \
            half8 bh = *(const half8*)&B_h[s * 16 + fr][fg * 8];                \
            _Pragma("unroll")                                                   \
            for (int mi = 0; mi < 2; ++mi)                                      \
                acc[mi][s] = __builtin_amdgcn_mfma_f32_16x16x32_f16(ah[mi], bh, acc[mi][s], 0, 0, 0); \
        }                                                                       \
    }

    G2_PRELOAD(A, 0);
    G2_STAGE(A);
    __syncthreads();
    G2_PRELOAD(B, 32);

    for (int kk = 0; kk < I_DIM; kk += 64) {
        if (kk + 64 < I_DIM) G2_PRELOAD(A, kk + 64);
        G2_COMPUTE();
        __syncthreads();
        G2_STAGE(B);
        __syncthreads();
        if (kk + 96 < I_DIM) G2_PRELOAD(B, kk + 96);
        G2_COMPUTE();
        __syncthreads();
        if (kk + 64 < I_DIM) { G2_STAGE(A); __syncthreads(); }
    }
#undef G2_PRELOAD
#undef G2_STAGE
#undef G2_COMPUTE

    const float* b2p = b2 + (size_t)e * H_DIM + n0;
    #pragma unroll
    for (int mi = 0; mi < 2; ++mi) {
        #pragma unroll
        for (int s = 0; s < 4; ++s) {
            #pragma unroll
            for (int r4 = 0; r4 < 4; ++r4) {
                int rt = r0 + mi * 16 + fg * 4 + r4;
                if (rt >= rows) continue;
                int tok = toks[rt];
                float wgt = wts[rt];
                int c = s * 16 + fr;
                atomicAdd(out + (size_t)tok * H_DIM + n0 + c, wgt * (acc[mi][s][r4] + b2p[c]));
            }
        }
    }
}

// ---------------- launch ----------------
extern "C" void kernel_launch(void* const* d_in, const int* in_sizes, int n_in,
                              void* d_out, int out_size, void* d_ws, size_t ws_size,
                              hipStream_t stream)
{
    const float* x     = (const float*)d_in[0];
    const float* scale = (const float*)d_in[1];
    const float* gw    = (const float*)d_in[2];
    const float* gb    = (const float*)d_in[3];
    const float* w1    = (const float*)d_in[4];
    const float* b1    = (const float*)d_in[5];
    const float* w2    = (const float*)d_in[6];
    const float* b2    = (const float*)d_in[7];
    float* out = (float*)d_out;

    char* ws = (char*)d_ws;
    f16* th    = (f16*)ws;                                 ws += (size_t)T_TOK * H_DIM * 2;
    f16* h_buf = (f16*)ws;                                 ws += (size_t)NSLOT * I_DIM * 2;
    float* topk_w        = (float*)ws;                     ws += NSLOT * 4;
    float* expert_wts    = (float*)ws;                     ws += NSLOT * 4;
    int*   topk_idx      = (int*)ws;                       ws += NSLOT * 4;
    int*   expert_tokens = (int*)ws;                       ws += NSLOT * 4;
    int*   offsets       = (int*)ws;

    hipLaunchKernelGGL(k_rms_router, dim3(T_TOK), dim3(256), 0, stream,
                       x, scale, gw, gb, th, out, topk_idx, topk_w);
    hipLaunchKernelGGL(k_route, dim3(1), dim3(256), 0, stream,
                       topk_idx, topk_w, offsets, expert_tokens, expert_wts);
    hipLaunchKernelGGL(k_gemm1, dim3(I_DIM / 64, T_TOK / BM, NEXP), dim3(256), 0, stream,
                       th, w1, b1, expert_tokens, offsets, h_buf);
    hipLaunchKernelGGL(k_gemm2, dim3(H_DIM / 64, T_TOK / BM, NEXP), dim3(256), 0, stream,
                       h_buf, w2, b2, expert_tokens, expert_wts, offsets, out);
}

// Round 10
// 336.340 us; speedup vs baseline: 1.5721x; 1.5721x over previous
//
#include <hip/hip_runtime.h>
#include <hip/hip_bf16.h>
#include <cstddef>

#define T_TOK 2048
#define H_DIM 768
#define NEXP 16
#define KSEL 4
#define I_DIM 768
#define TWO_I 1536
#define NSLOT (T_TOK*KSEL)
#define ALPHA 1.702f
#define LIMIT 7.0f
#define EPS_RMS 1e-5f
#define BM 128

typedef _Float16 f16;
typedef _Float16 half8 __attribute__((ext_vector_type(8)));
typedef float f32x4 __attribute__((ext_vector_type(4)));

// ---------------- Kernel 1: RMSNorm + router (fp32) + residual init ----------------
__global__ __launch_bounds__(256) void k_rms_router(
    const float* __restrict__ x, const float* __restrict__ scale,
    const float* __restrict__ gw, const float* __restrict__ gb,
    f16* __restrict__ th, float* __restrict__ out,
    int* __restrict__ topk_idx, float* __restrict__ topk_w)
{
    int t = blockIdx.x;
    int tid = threadIdx.x;
    int lane = tid & 63, wid = tid >> 6;
    __shared__ float ts[H_DIM];
    __shared__ float red[8];
    __shared__ float logits[NEXP];

    const float* xr = x + (size_t)t * H_DIM;
    float v0 = xr[tid], v1 = xr[tid + 256], v2 = xr[tid + 512];
    float ss = v0*v0 + v1*v1 + v2*v2;
    #pragma unroll
    for (int m = 32; m >= 1; m >>= 1) ss += __shfl_xor(ss, m, 64);
    if (lane == 0) red[wid] = ss;
    __syncthreads();
    if (tid == 0) {
        float tot = red[0] + red[1] + red[2] + red[3];
        red[4] = rsqrtf(tot / (float)H_DIM + EPS_RMS);
    }
    __syncthreads();
    float rinv = red[4];
    float t0 = v0 * rinv * scale[tid];
    float t1 = v1 * rinv * scale[tid + 256];
    float t2 = v2 * rinv * scale[tid + 512];
    ts[tid] = t0; ts[tid + 256] = t1; ts[tid + 512] = t2;
    size_t base = (size_t)t * H_DIM;
    th[base + tid] = (f16)t0;
    th[base + tid + 256] = (f16)t1;
    th[base + tid + 512] = (f16)t2;
    float* op = out + base;
    op[tid] = v0; op[tid + 256] = v1; op[tid + 512] = v2;
    __syncthreads();

    #pragma unroll
    for (int ee = 0; ee < 4; ++ee) {
        int e = wid * 4 + ee;
        const float* g = gw + (size_t)e * H_DIM;
        float p = 0.f;
        for (int i = lane; i < H_DIM; i += 64) p += ts[i] * g[i];
        #pragma unroll
        for (int m = 32; m >= 1; m >>= 1) p += __shfl_xor(p, m, 64);
        if (lane == 0) logits[e] = p + gb[e];
    }
    __syncthreads();

    if (tid == 0) {
        float lg[NEXP];
        #pragma unroll
        for (int e = 0; e < NEXP; ++e) lg[e] = logits[e];
        float vals[KSEL]; int idx[KSEL];
        #pragma unroll
        for (int k = 0; k < KSEL; ++k) {
            float best = -1e30f; int bi = 0;
            for (int e = 0; e < NEXP; ++e)
                if (lg[e] > best) { best = lg[e]; bi = e; }   // strict > => lowest index on ties
            vals[k] = best; idx[k] = bi; lg[bi] = -1e30f;
        }
        float mx = vals[0], sum = 0.f, ex[KSEL];
        #pragma unroll
        for (int k = 0; k < KSEL; ++k) { ex[k] = expf(vals[k] - mx); sum += ex[k]; }
        float inv = 1.f / sum;
        #pragma unroll
        for (int k = 0; k < KSEL; ++k) {
            topk_idx[t * KSEL + k] = idx[k];
            topk_w[t * KSEL + k] = ex[k] * inv;   // softmax/K * K cancels
        }
    }
}

// ---------------- Kernel 2: fused count + scan + scatter (1 block) ----------------
__global__ __launch_bounds__(256) void k_route(
    const int* __restrict__ topk_idx, const float* __restrict__ topk_w,
    int* __restrict__ offsets,
    int* __restrict__ expert_tokens, float* __restrict__ expert_wts)
{
    __shared__ int cnt[NEXP];
    __shared__ int cur[NEXP];
    int tid = threadIdx.x;
    if (tid < NEXP) cnt[tid] = 0;
    __syncthreads();
    int base = tid * 32;                       // NSLOT = 256*32
    for (int j = 0; j < 32; ++j) atomicAdd(&cnt[topk_idx[base + j]], 1);
    __syncthreads();
    if (tid == 0) {
        int acc = 0;
        for (int e = 0; e < NEXP; ++e) {
            offsets[e] = acc; cur[e] = acc; acc += cnt[e];
        }
        offsets[NEXP] = acc;
    }
    __syncthreads();
    for (int j = 0; j < 32; ++j) {
        int i = base + j;
        int e = topk_idx[i];
        int slot = atomicAdd(&cur[e], 1);
        expert_tokens[slot] = i >> 2;          // i = t*KSEL + k
        expert_wts[slot] = topk_w[i];
    }
}

// ---------------- Kernel 3: GEMM1 (H->2I) fp16 MFMA, depth-1 prefetch, XCD swizzle ----------------
__global__ __launch_bounds__(256) void k_gemm1(
    const f16* __restrict__ th, const float* __restrict__ w1,
    const float* __restrict__ b1,
    const int* __restrict__ expert_tokens, const int* __restrict__ offsets,
    f16* __restrict__ h_buf)
{
    // bijective XCD-chunked swizzle: 3072 blocks = 8 XCDs x 384; m-tile (y) fastest
    int lid = blockIdx.x + 12 * (blockIdx.y + 16 * blockIdx.z);
    int tl = (lid & 7) * 384 + (lid >> 3);
    int by = tl & 15;
    int bx = (tl >> 4) % 12;
    int e  = tl / 192;

    int beg = offsets[e];
    int cnt = offsets[e + 1] - beg;
    int m0 = by * BM;
    if (m0 >= cnt) return;
    int n0 = bx * 64;
    int rows = min(BM, cnt - m0);

    __shared__ f16 A_h[BM][40];
    __shared__ f16 Bg_h[64][40];
    __shared__ f16 Bn_h[64][40];
    __shared__ int toks[BM];

    int tid = threadIdx.x;
    int w = tid >> 6, lane = tid & 63;
    if (tid < BM) toks[tid] = (tid < rows) ? expert_tokens[beg + m0 + tid] : -1;
    __syncthreads();

    int arow = tid >> 2, ach = tid & 3;
    int tokA0 = toks[arow], tokA1 = toks[arow + 64];
    int fr = lane & 15, fg = lane >> 4;
    int wr = w >> 1, wc = w & 1;

    const float* bgp = w1 + ((size_t)e * H_DIM + w * 8) * TWO_I + n0 + lane;

    half8 z8;
    #pragma unroll
    for (int j = 0; j < 8; ++j) z8[j] = (f16)0.f;

    f32x4 zero4 = {0.f, 0.f, 0.f, 0.f};
    f32x4 accg[4][2], accn[4][2];
    #pragma unroll
    for (int mi = 0; mi < 4; ++mi)
        #pragma unroll
        for (int s = 0; s < 2; ++s) { accg[mi][s] = zero4; accn[mi][s] = zero4; }

    half8 pah0, pah1;
    float pbg[8], pbn[8];

#define G1_PRELOAD(KK)                                                          \
    do {                                                                        \
        pah0 = (tokA0 >= 0) ? *(const half8*)(th + (size_t)tokA0 * H_DIM + (KK) + ach * 8) : z8; \
        pah1 = (tokA1 >= 0) ? *(const half8*)(th + (size_t)tokA1 * H_DIM + (KK) + ach * 8) : z8; \
        _Pragma("unroll")                                                       \
        for (int j = 0; j < 8; ++j) {                                           \
            pbg[j] = bgp[(size_t)((KK) + j) * TWO_I];                           \
            pbn[j] = bgp[(size_t)((KK) + j) * TWO_I + I_DIM];                   \
        }                                                                       \
    } while (0)

    G1_PRELOAD(0);

    for (int kk = 0; kk < H_DIM; kk += 32) {
        __syncthreads();                       // previous tile consumed
        *(half8*)&A_h[arow][ach * 8] = pah0;
        *(half8*)&A_h[arow + 64][ach * 8] = pah1;
        half8 vgh, vnh;
        #pragma unroll
        for (int j = 0; j < 8; ++j) {
            vgh[j] = (f16)pbg[j];
            vnh[j] = (f16)pbn[j];
        }
        *(half8*)&Bg_h[lane][w * 8] = vgh;
        *(half8*)&Bn_h[lane][w * 8] = vnh;
        __syncthreads();                       // tile ready
        if (kk + 32 < H_DIM) G1_PRELOAD(kk + 32);   // overlaps compute

        half8 ah[4];
        #pragma unroll
        for (int mi = 0; mi < 4; ++mi)
            ah[mi] = *(const half8*)&A_h[wr * 64 + mi * 16 + fr][fg * 8];
        #pragma unroll
        for (int s = 0; s < 2; ++s) {
            int nb = wc * 32 + s * 16 + fr;
            half8 bgh = *(const half8*)&Bg_h[nb][fg * 8];
            half8 bnh = *(const half8*)&Bn_h[nb][fg * 8];
            #pragma unroll
            for (int mi = 0; mi < 4; ++mi) {
                accg[mi][s] = __builtin_amdgcn_mfma_f32_16x16x32_f16(ah[mi], bgh, accg[mi][s], 0, 0, 0);
                accn[mi][s] = __builtin_amdgcn_mfma_f32_16x16x32_f16(ah[mi], bnh, accn[mi][s], 0, 0, 0);
            }
        }
    }
#undef G1_PRELOAD

    // epilogue: bias + SwiGLU, fp16 store (C/D map m89: col=lane&15, row=(lane>>4)*4+reg)
    const float* b1p = b1 + (size_t)e * TWO_I + n0;
    #pragma unroll
    for (int mi = 0; mi < 4; ++mi) {
        #pragma unroll
        for (int s = 0; s < 2; ++s) {
            #pragma unroll
            for (int r4 = 0; r4 < 4; ++r4) {
                int rt = wr * 64 + mi * 16 + fg * 4 + r4;
                if (rt >= rows) continue;
                int slot = beg + m0 + rt;
                int c = wc * 32 + s * 16 + fr;
                float hg = accg[mi][s][r4] + b1p[c];
                float hl2 = accn[mi][s][r4] + b1p[I_DIM + c];
                hg = fminf(hg, LIMIT);
                hl2 = fminf(fmaxf(hl2, -LIMIT), LIMIT);
                float sg = 1.f / (1.f + expf(-ALPHA * hg));
                h_buf[(size_t)slot * I_DIM + n0 + c] = (f16)(hg * sg * (hl2 + 1.f));
            }
        }
    }
}

// ---------------- Kernel 4: GEMM2 (I->H) fp16 MFMA, depth-1 prefetch, XCD swizzle ----------------
__global__ __launch_bounds__(256) void k_gemm2(
    const f16* __restrict__ h_buf, const float* __restrict__ w2,
    const float* __restrict__ b2,
    const int* __restrict__ expert_tokens, const float* __restrict__ expert_wts,
    const int* __restrict__ offsets, float* __restrict__ out)
{
    int lid = blockIdx.x + 12 * (blockIdx.y + 16 * blockIdx.z);
    int tl = (lid & 7) * 384 + (lid >> 3);
    int by = tl & 15;
    int bx = (tl >> 4) % 12;
    int e  = tl / 192;

    int beg = offsets[e];
    int cnt = offsets[e + 1] - beg;
    int m0 = by * BM;
    if (m0 >= cnt) return;
    int n0 = bx * 64;
    int rows = min(BM, cnt - m0);

    __shared__ f16 A_h[BM][40];
    __shared__ f16 B_h[64][40];
    __shared__ int   toks[BM];
    __shared__ float wts[BM];

    int tid = threadIdx.x;
    int w = tid >> 6, lane = tid & 63;
    if (tid < BM) {
        bool ok = tid < rows;
        toks[tid] = ok ? expert_tokens[beg + m0 + tid] : -1;
        wts[tid]  = ok ? expert_wts[beg + m0 + tid] : 0.f;
    }
    __syncthreads();

    int arow = tid >> 2, ach = tid & 3;
    bool aok0 = arow < rows, aok1 = (arow + 64) < rows;
    int fr = lane & 15, fg = lane >> 4;
    int r0 = w * 32;

    const float* bp = w2 + ((size_t)e * I_DIM + w * 8) * H_DIM + n0 + lane;

    half8 z8;
    #pragma unroll
    for (int j = 0; j < 8; ++j) z8[j] = (f16)0.f;

    f32x4 zero4 = {0.f, 0.f, 0.f, 0.f};
    f32x4 acc[2][4];
    #pragma unroll
    for (int mi = 0; mi < 2; ++mi)
        #pragma unroll
        for (int s = 0; s < 4; ++s) acc[mi][s] = zero4;

    half8 pah0, pah1;
    float pb[8];

#define G2_PRELOAD(KK)                                                          \
    do {                                                                        \
        pah0 = aok0 ? *(const half8*)(h_buf + (size_t)(beg + m0 + arow) * I_DIM + (KK) + ach * 8) : z8; \
        pah1 = aok1 ? *(const half8*)(h_buf + (size_t)(beg + m0 + arow + 64) * I_DIM + (KK) + ach * 8) : z8; \
        _Pragma("unroll")                                                       \
        for (int j = 0; j < 8; ++j) pb[j] = bp[(size_t)((KK) + j) * H_DIM];     \
    } while (0)

    G2_PRELOAD(0);

    for (int kk = 0; kk < I_DIM; kk += 32) {
        __syncthreads();
        *(half8*)&A_h[arow][ach * 8] = pah0;
        *(half8*)&A_h[arow + 64][ach * 8] = pah1;
        half8 vbh;
        #pragma unroll
        for (int j = 0; j < 8; ++j) vbh[j] = (f16)pb[j];
        *(half8*)&B_h[lane][w * 8] = vbh;
        __syncthreads();
        if (kk + 32 < I_DIM) G2_PRELOAD(kk + 32);

        half8 ah[2];
        #pragma unroll
        for (int mi = 0; mi < 2; ++mi)
            ah[mi] = *(const half8*)&A_h[r0 + mi * 16 + fr][fg * 8];
        #pragma unroll
        for (int s = 0; s < 4; ++s) {
            half8 bh = *(const half8*)&B_h[s * 16 + fr][fg * 8];
            #pragma unroll
            for (int mi = 0; mi < 2; ++mi)
                acc[mi][s] = __builtin_amdgcn_mfma_f32_16x16x32_f16(ah[mi], bh, acc[mi][s], 0, 0, 0);
        }
    }
#undef G2_PRELOAD

    const float* b2p = b2 + (size_t)e * H_DIM + n0;
    #pragma unroll
    for (int mi = 0; mi < 2; ++mi) {
        #pragma unroll
        for (int s = 0; s < 4; ++s) {
            #pragma unroll
            for (int r4 = 0; r4 < 4; ++r4) {
                int rt = r0 + mi * 16 + fg * 4 + r4;
                if (rt >= rows) continue;
                int tok = toks[rt];
                float wgt = wts[rt];
                int c = s * 16 + fr;
                atomicAdd(out + (size_t)tok * H_DIM + n0 + c, wgt * (acc[mi][s][r4] + b2p[c]));
            }
        }
    }
}

// ---------------- launch ----------------
extern "C" void kernel_launch(void* const* d_in, const int* in_sizes, int n_in,
                              void* d_out, int out_size, void* d_ws, size_t ws_size,
                              hipStream_t stream)
{
    const float* x     = (const float*)d_in[0];
    const float* scale = (const float*)d_in[1];
    const float* gw    = (const float*)d_in[2];
    const float* gb    = (const float*)d_in[3];
    const float* w1    = (const float*)d_in[4];
    const float* b1    = (const float*)d_in[5];
    const float* w2    = (const float*)d_in[6];
    const float* b2    = (const float*)d_in[7];
    float* out = (float*)d_out;

    char* ws = (char*)d_ws;
    f16* th    = (f16*)ws;                                 ws += (size_t)T_TOK * H_DIM * 2;
    f16* h_buf = (f16*)ws;                                 ws += (size_t)NSLOT * I_DIM * 2;
    float* topk_w        = (float*)ws;                     ws += NSLOT * 4;
    float* expert_wts    = (float*)ws;                     ws += NSLOT * 4;
    int*   topk_idx      = (int*)ws;                       ws += NSLOT * 4;
    int*   expert_tokens = (int*)ws;                       ws += NSLOT * 4;
    int*   offsets       = (int*)ws;

    hipLaunchKernelGGL(k_rms_router, dim3(T_TOK), dim3(256), 0, stream,
                       x, scale, gw, gb, th, out, topk_idx, topk_w);
    hipLaunchKernelGGL(k_route, dim3(1), dim3(256), 0, stream,
                       topk_idx, topk_w, offsets, expert_tokens, expert_wts);
    hipLaunchKernelGGL(k_gemm1, dim3(I_DIM / 64, T_TOK / BM, NEXP), dim3(256), 0, stream,
                       th, w1, b1, expert_tokens, offsets, h_buf);
    hipLaunchKernelGGL(k_gemm2, dim3(H_DIM / 64, T_TOK / BM, NEXP), dim3(256), 0, stream,
                       h_buf, w2, b2, expert_tokens, expert_wts, offsets, out);
}